// Round 3
// baseline (3078.453 us; speedup 1.0000x reference)
//
#include <hip/hip_runtime.h>

// SimpleLSTM B=128,T=8192,H=96. R16: symmetric matrix pipes + VALU shaves.
// R15 post-mortem recalibrated the model: counters normalize by 256 CUs but
// only 64 are active -> per-active-SIMD MfmaUtil ~34%, VALUBusy ~39%. The
// 16x16x32 MFMA occupies a SIMD's matrix pipe ~17 cyc, so 18 MFMAs/wave =
// ~306 cyc/step of pipe time; the y-wave shared SIMD0 with gate wave 0 and
// its 3 MFMAs made SIMD0 the barrier straggler (21x17=357). R16:
//  (1) y-wave computes y = w_out . h via VALU (cvt+fmaf, 3 parallel chains)
//      + 2 __shfl_xor cross-quad reduce -- zero matrix-pipe ops on SIMD0;
//  (2) s_setprio(1) on gate waves (role-split: gate wave wins SIMD0 issue);
//  (3) #pragma unroll 2 -> parity p compile-time, no per-step addr selects;
//  (4) select tree depth 5 -> 3 (binary, precomputed lane masks);
//  (5) h-write predicate dropped: lanes cc=6,7 bitwise-duplicate cc=0,1
//      (same cell, same inputs) -> benign same-value write, no exec juggling;
//  (6) x-prefetch clamp dropped (x_s +8 pad absorbs the over-read).
// Carried: 2 batches in B columns, 4 gate waves x 6 tiles, permuted W rows,
// exp2-domain prescale, named scalars, pinned A-frags, y ring flush by 128.

#define T_LEN 8192
#define H_DIM 96
#define NTHR  320   // 5 waves: 4 gate waves + 1 y/flush wave
#define CHUNK 128
#define LOG2E 1.44269504f

typedef float    f32x4 __attribute__((ext_vector_type(4)));
typedef _Float16 half8 __attribute__((ext_vector_type(8)));

#define MFMA16(A, B, C)                                                        \
    __builtin_amdgcn_mfma_f32_16x16x32_f16(__builtin_bit_cast(half8, (A)),     \
                                           __builtin_bit_cast(half8, (B)),     \
                                           (C), 0, 0, 0)

__device__ __forceinline__ float sig2(float s) {   // sigmoid, s = log2e*pre
    return __builtin_amdgcn_rcpf(1.0f + __builtin_amdgcn_exp2f(-s));
}
__device__ __forceinline__ float tanh2(float sg) { // tanh, sg = 2log2e*pre
    return 1.0f - 2.0f * __builtin_amdgcn_rcpf(1.0f + __builtin_amdgcn_exp2f(sg));
}

__device__ __forceinline__ f32x4 load_afrag(const float* __restrict__ w_hh,
                                            const float* __restrict__ w_out,
                                            int mt, int kt, int m, int quad) {
    half8 f;
    if (mt < 24) {
        const int r = m & 3;                       // gate: 0=i 1=f 2=g 3=o
        const float scale = (r == 2) ? 2.0f * LOG2E : LOG2E;
        const int orig = r * 96 + 4 * mt + (m >> 2);
        const float* src = w_hh + orig * H_DIM + kt * 32 + quad * 8;
        #pragma unroll
        for (int jj = 0; jj < 8; ++jj) f[jj] = (_Float16)(scale * src[jj]);
    } else {  // unused-by-gates path (y-wave's af regs are dummies)
        #pragma unroll
        for (int jj = 0; jj < 8; ++jj)
            f[jj] = (m == 0) ? (_Float16)w_out[kt * 32 + quad * 8 + jj]
                             : (_Float16)0.0f;
    }
    return __builtin_bit_cast(f32x4, f);
}

__global__ __launch_bounds__(NTHR, 2) void lstm_mfma16_kernel(
    const float* __restrict__ x,      // [B, T]
    const float* __restrict__ w_ih,   // [4H]
    const float* __restrict__ w_hh,   // [4H, H]
    const float* __restrict__ b_ih,   // [4H]
    const float* __restrict__ b_hh,   // [4H]
    const float* __restrict__ w_out,  // [H]
    const float* __restrict__ b_out,  // [1]
    float* __restrict__ y)            // [B, T]
{
    const int tid  = threadIdx.x;
    const int wv   = tid >> 6;        // wave 0..3 = gates, 4 = y/flush
    const int lane = tid & 63;
    const int m    = lane & 15;       // A-row / D-column index
    const int quad = lane >> 4;       // D row group / B K-chunk
    const int cc   = m & 7;           // within-batch column
    const int bsub = m >> 3;          // 0: batch 2b, 1: batch 2b+1

    __shared__ __align__(16) _Float16 h_s[2][2][H_DIM];       // [buf][bsub][cell]
    __shared__ __align__(16) float    y_buf[2][2][CHUNK];     // [bsub][ring][i]
    __shared__ __align__(16) float    x_s[2][T_LEN + 8];      // +8 pad

    // ---- stage both batches' x into LDS
    {
        const float* xpair = x + (size_t)(2 * blockIdx.x) * T_LEN;
        for (int i = tid * 4; i < T_LEN; i += NTHR * 4) {
            *reinterpret_cast<f32x4*>(&x_s[0][i]) =
                *reinterpret_cast<const f32x4*>(&xpair[i]);
            *reinterpret_cast<f32x4*>(&x_s[1][i]) =
                *reinterpret_cast<const f32x4*>(&xpair[T_LEN + i]);
        }
    }

    // ---- A fragments (named, pinned). Gate wave wv owns tiles 6wv..6wv+5.
    const int mt0 = 6 * wv;
    f32x4 af00 = load_afrag(w_hh, w_out, mt0 + 0, 0, m, quad);
    f32x4 af01 = load_afrag(w_hh, w_out, mt0 + 0, 1, m, quad);
    f32x4 af02 = load_afrag(w_hh, w_out, mt0 + 0, 2, m, quad);
    f32x4 af10 = load_afrag(w_hh, w_out, mt0 + 1, 0, m, quad);
    f32x4 af11 = load_afrag(w_hh, w_out, mt0 + 1, 1, m, quad);
    f32x4 af12 = load_afrag(w_hh, w_out, mt0 + 1, 2, m, quad);
    f32x4 af20 = load_afrag(w_hh, w_out, mt0 + 2, 0, m, quad);
    f32x4 af21 = load_afrag(w_hh, w_out, mt0 + 2, 1, m, quad);
    f32x4 af22 = load_afrag(w_hh, w_out, mt0 + 2, 2, m, quad);
    f32x4 af30 = load_afrag(w_hh, w_out, mt0 + 3, 0, m, quad);
    f32x4 af31 = load_afrag(w_hh, w_out, mt0 + 3, 1, m, quad);
    f32x4 af32 = load_afrag(w_hh, w_out, mt0 + 3, 2, m, quad);
    f32x4 af40 = load_afrag(w_hh, w_out, mt0 + 4, 0, m, quad);
    f32x4 af41 = load_afrag(w_hh, w_out, mt0 + 4, 1, m, quad);
    f32x4 af42 = load_afrag(w_hh, w_out, mt0 + 4, 2, m, quad);
    f32x4 af50 = load_afrag(w_hh, w_out, mt0 + 5, 0, m, quad);
    f32x4 af51 = load_afrag(w_hh, w_out, mt0 + 5, 1, m, quad);
    f32x4 af52 = load_afrag(w_hh, w_out, mt0 + 5, 2, m, quad);
    f32x4 zero4 = {0.f, 0.f, 0.f, 0.f};
    asm volatile("" : "+v"(af00), "+v"(af01), "+v"(af02), "+v"(af10),
                      "+v"(af11), "+v"(af12), "+v"(af20));
    asm volatile("" : "+v"(af21), "+v"(af22), "+v"(af30), "+v"(af31),
                      "+v"(af32), "+v"(af40), "+v"(af41));
    asm volatile("" : "+v"(af42), "+v"(af50), "+v"(af51), "+v"(af52),
                      "+v"(zero4));

    // ---- y-wave: w_out slices matching this lane's B-frag k-positions
    // (f32, kept full precision; 6 named f32x4 vectors, constant indexing)
    f32x4 woa0 = {0,0,0,0}, woa1 = {0,0,0,0}, wob0 = {0,0,0,0},
          wob1 = {0,0,0,0}, woc0 = {0,0,0,0}, woc1 = {0,0,0,0};
    if (wv == 4) {
        woa0 = *reinterpret_cast<const f32x4*>(&w_out[quad * 8]);
        woa1 = *reinterpret_cast<const f32x4*>(&w_out[quad * 8 + 4]);
        wob0 = *reinterpret_cast<const f32x4*>(&w_out[32 + quad * 8]);
        wob1 = *reinterpret_cast<const f32x4*>(&w_out[32 + quad * 8 + 4]);
        woc0 = *reinterpret_cast<const f32x4*>(&w_out[64 + quad * 8]);
        woc1 = *reinterpret_cast<const f32x4*>(&w_out[64 + quad * 8 + 4]);
    }

    // ---- per-lane cell params (gate waves; exp2-domain prescaled)
    const int sel  = (cc >= 6) ? (cc - 6) : cc;
    const int cell = (wv < 4) ? (24 * wv + 4 * sel + quad) : 0;
    const bool s_b0 = sel & 1;
    const bool s_b1 = (sel >> 1) & 1;
    const bool s_b2 = (sel >> 2) & 1;
    const float bias_i = LOG2E * (b_ih[0 * H_DIM + cell] + b_hh[0 * H_DIM + cell]);
    const float bias_f = LOG2E * (b_ih[1 * H_DIM + cell] + b_hh[1 * H_DIM + cell]);
    const float bias_g = 2.0f * LOG2E * (b_ih[2 * H_DIM + cell] + b_hh[2 * H_DIM + cell]);
    const float bias_o = LOG2E * (b_ih[3 * H_DIM + cell] + b_hh[3 * H_DIM + cell]);
    const float wih_i  = LOG2E * w_ih[0 * H_DIM + cell];
    const float wih_f  = LOG2E * w_ih[1 * H_DIM + cell];
    const float wih_g  = 2.0f * LOG2E * w_ih[2 * H_DIM + cell];
    const float wih_o  = LOG2E * w_ih[3 * H_DIM + cell];
    const float bout   = b_out[0];
    float c = 0.f;
    if (tid < 2 * H_DIM) (&h_s[0][0][0])[tid] = (_Float16)0.0f;  // buf 0
    __syncthreads();

    if (wv < 4) __builtin_amdgcn_s_setprio(1);  // gates win SIMD0 arbitration

    float x_cur_next = x_s[bsub][0];  // register prefetch of x[it] (own batch)

    // iter it: gate waves read h_{it-1} (h_s[it&1]) and produce h_it;
    // y-wave reads the same buffer and stores y_{it-1}.
    #pragma unroll 2
    for (int it = 0; it <= T_LEN + 1; ++it) {
        const int p = it & 1;

        if (wv < 4) {
            // ------------- gate wave -------------
            if (it < T_LEN) {
                const f32x4 b0 = *reinterpret_cast<const f32x4*>(&h_s[p][bsub][quad * 8]);
                const f32x4 b1 = *reinterpret_cast<const f32x4*>(&h_s[p][bsub][32 + quad * 8]);
                const f32x4 b2 = *reinterpret_cast<const f32x4*>(&h_s[p][bsub][64 + quad * 8]);
                const float x_cur = x_cur_next;
                x_cur_next = x_s[bsub][it + 1];  // pad absorbs over-read

                f32x4 acc0 = MFMA16(af00, b0, zero4);
                f32x4 acc1 = MFMA16(af10, b0, zero4);
                f32x4 acc2 = MFMA16(af20, b0, zero4);
                f32x4 acc3 = MFMA16(af30, b0, zero4);
                f32x4 acc4 = MFMA16(af40, b0, zero4);
                f32x4 acc5 = MFMA16(af50, b0, zero4);
                acc0 = MFMA16(af01, b1, acc0);
                acc1 = MFMA16(af11, b1, acc1);
                acc2 = MFMA16(af21, b1, acc2);
                acc3 = MFMA16(af31, b1, acc3);
                acc4 = MFMA16(af41, b1, acc4);
                acc5 = MFMA16(af51, b1, acc5);
                acc0 = MFMA16(af02, b2, acc0);
                acc1 = MFMA16(af12, b2, acc1);
                acc2 = MFMA16(af22, b2, acc2);
                acc3 = MFMA16(af32, b2, acc3);
                acc4 = MFMA16(af42, b2, acc4);
                acc5 = MFMA16(af52, b2, acc5);

                // depth-3 binary select
                const f32x4 t0 = s_b0 ? acc1 : acc0;
                const f32x4 t1 = s_b0 ? acc3 : acc2;
                const f32x4 t2 = s_b0 ? acc5 : acc4;
                const f32x4 g4 = s_b2 ? t2 : (s_b1 ? t1 : t0);

                const float s0 = g4.x + fmaf(x_cur, wih_i, bias_i);
                const float s1 = g4.y + fmaf(x_cur, wih_f, bias_f);
                const float s2 = g4.z + fmaf(x_cur, wih_g, bias_g);
                const float s3 = g4.w + fmaf(x_cur, wih_o, bias_o);
                const float ig = sig2(s0);
                const float fg = sig2(s1);
                const float gg = tanh2(s2);
                const float og = sig2(s3);
                c = fmaf(fg, c, ig * gg);
                const float h = og * tanh2(2.0f * LOG2E * c);
                // all 64 lanes write; cc=6,7 bitwise-duplicate cc=0,1 (benign)
                h_s[p ^ 1][bsub][cell] = (_Float16)h;
            }
        } else {
            // ------------- y / flush wave (VALU only, no matrix pipe) ------
            if (it <= T_LEN) {
                const f32x4 b0 = *reinterpret_cast<const f32x4*>(&h_s[p][bsub][quad * 8]);
                const f32x4 b1 = *reinterpret_cast<const f32x4*>(&h_s[p][bsub][32 + quad * 8]);
                const f32x4 b2 = *reinterpret_cast<const f32x4*>(&h_s[p][bsub][64 + quad * 8]);
                const half8 hb0 = __builtin_bit_cast(half8, b0);
                const half8 hb1 = __builtin_bit_cast(half8, b1);
                const half8 hb2 = __builtin_bit_cast(half8, b2);
                float a0 = 0.f, a1 = 0.f, a2 = 0.f;   // 3 parallel chains
                a0 = fmaf((float)hb0[0], woa0.x, a0);
                a1 = fmaf((float)hb1[0], wob0.x, a1);
                a2 = fmaf((float)hb2[0], woc0.x, a2);
                a0 = fmaf((float)hb0[1], woa0.y, a0);
                a1 = fmaf((float)hb1[1], wob0.y, a1);
                a2 = fmaf((float)hb2[1], woc0.y, a2);
                a0 = fmaf((float)hb0[2], woa0.z, a0);
                a1 = fmaf((float)hb1[2], wob0.z, a1);
                a2 = fmaf((float)hb2[2], woc0.z, a2);
                a0 = fmaf((float)hb0[3], woa0.w, a0);
                a1 = fmaf((float)hb1[3], wob0.w, a1);
                a2 = fmaf((float)hb2[3], woc0.w, a2);
                a0 = fmaf((float)hb0[4], woa1.x, a0);
                a1 = fmaf((float)hb1[4], wob1.x, a1);
                a2 = fmaf((float)hb2[4], woc1.x, a2);
                a0 = fmaf((float)hb0[5], woa1.y, a0);
                a1 = fmaf((float)hb1[5], wob1.y, a1);
                a2 = fmaf((float)hb2[5], woc1.y, a2);
                a0 = fmaf((float)hb0[6], woa1.z, a0);
                a1 = fmaf((float)hb1[6], wob1.z, a1);
                a2 = fmaf((float)hb2[6], woc1.z, a2);
                a0 = fmaf((float)hb0[7], woa1.w, a0);
                a1 = fmaf((float)hb1[7], wob1.w, a1);
                a2 = fmaf((float)hb2[7], woc1.w, a2);
                float acc = a0 + a1 + a2;             // this lane's 24 terms
                acc += __shfl_xor(acc, 32, 64);       // quad ^2
                acc += __shfl_xor(acc, 16, 64);       // quad ^1 -> full dot
                if ((lane == 0 || lane == 8) && it > 0)
                    y_buf[bsub][((it - 1) >> 7) & 1][(it - 1) & (CHUNK - 1)] =
                        acc + bout;
            }
            // ring flush: chunk [it-1-CHUNK, it-1) complete
            if ((it & (CHUNK - 1)) == 1 && it > 1) {
                const int base = it - 1 - CHUNK;
                const int pb   = (base >> 7) & 1;
                const int bsel = lane >> 5;
                const int li   = lane & 31;
                const f32x4 v =
                    *reinterpret_cast<const f32x4*>(&y_buf[bsel][pb][li * 4]);
                float* yrow = y + (size_t)(2 * blockIdx.x + bsel) * T_LEN;
                *reinterpret_cast<f32x4*>(&yrow[base + li * 4]) = v;
            }
        }
        __syncthreads();  // h_s[p^1] + y_buf ready (5-wave barrier)
    }
}

extern "C" void kernel_launch(void* const* d_in, const int* in_sizes, int n_in,
                              void* d_out, int out_size, void* d_ws, size_t ws_size,
                              hipStream_t stream) {
    const float* x     = (const float*)d_in[0];
    const float* w_ih  = (const float*)d_in[1];
    const float* w_hh  = (const float*)d_in[2];
    const float* b_ih  = (const float*)d_in[3];
    const float* b_hh  = (const float*)d_in[4];
    const float* w_out = (const float*)d_in[5];
    const float* b_out = (const float*)d_in[6];
    float* y = (float*)d_out;

    const int NBLK = 64;  // 2 batches per block (packed into B columns)
    lstm_mfma16_kernel<<<dim3(NBLK), dim3(NTHR), 0, stream>>>(
        x, w_ih, w_hh, b_ih, b_hh, w_out, b_out, y);
}